// Round 19
// baseline (241.522 us; speedup 1.0000x reference)
//
#include <hip/hip_runtime.h>
#include <hip/hip_bf16.h>

#define BB 4
#define SS 4096
#define EE 64
#define DD 512
#define KVBLK 64
#define NQT 16  // 64-wide KV tiles per quarter

typedef __attribute__((ext_vector_type(4))) float f32x4;
typedef __attribute__((ext_vector_type(8))) _Float16 f16x8;
typedef unsigned short u16;
typedef unsigned int u32;

__device__ __forceinline__ u16 f2h(float f) {
  _Float16 h = (_Float16)f;
  return __builtin_bit_cast(u16, h);
}
__device__ __forceinline__ float h2f(u16 b) {
  return (float)__builtin_bit_cast(_Float16, b);
}

// ---------------- K1: fused weight-fold: G=Wq@Wk^T, g2=Wk@bq, Wf=Wv@Wo, bf=bv@Wo ----
__global__ __launch_bounds__(256) void wgfuse(
    const float* __restrict__ Wq, const float* __restrict__ bq,
    const float* __restrict__ Wk, const float* __restrict__ Wv,
    const float* __restrict__ bv, const float* __restrict__ Wo,
    float* __restrict__ G, float* __restrict__ g2,
    float* __restrict__ Wf, float* __restrict__ bf) {
  __shared__ float red[4][64];
  const int tid = threadIdx.x;
  const int d = tid & 63, kq = tid >> 6;
  const int e = blockIdx.x;
  float a = 0.f;
  if (e < 65) {
    const float* src = (e < 64) ? &Wq[(size_t)e * DD] : bq;
    #pragma unroll 4
    for (int k = kq * 128; k < (kq + 1) * 128; ++k)
      a += src[k] * Wk[(size_t)d * DD + k];
  } else {
    const int e2 = e - 65;
    const float* src = (e2 < 64) ? &Wv[(size_t)e2 * DD] : bv;
    #pragma unroll 4
    for (int k = kq * 128; k < (kq + 1) * 128; ++k)
      a += src[k] * Wo[(size_t)k * EE + d];
  }
  red[kq][d] = a;
  __syncthreads();
  if (tid < 64) {
    float s = (red[0][tid] + red[1][tid]) + (red[2][tid] + red[3][tid]);
    if (e < 64) G[e * 64 + tid] = s;
    else if (e == 64) g2[tid] = s;
    else if (e < 129) Wf[(e - 65) * EE + tid] = s;
    else bf[tid] = s;
  }
}

// ---------------- K2: grid-fused prep: mask_scan (bid<512) + proj64 (bid>=512) ----
__global__ __launch_bounds__(256) void prep(
    const float* __restrict__ x, const float* __restrict__ G,
    const float* __restrict__ g2, const float* __restrict__ Wf,
    const float* __restrict__ bf, const float* __restrict__ mask,
    u16* __restrict__ ubuf, u16* __restrict__ xh, float* __restrict__ cbuf,
    u16* __restrict__ vwt, unsigned char* __restrict__ flags) {
  __shared__ float xs[64][EE];
  __shared__ float gs[EE][64];
  __shared__ float wfs[EE][64];
  __shared__ float g2s[64];
  __shared__ float bfs[64];
  __shared__ int fl[32];
  const int tid = threadIdx.x;

  if (blockIdx.x < 512) {
    // ---- mask_scan body: contiguous 4KB bursts ----
    const int bid = blockIdx.x;
    const int tq = bid & 3;
    const int qb = (bid >> 2) & 31;
    const int b = bid >> 7;
    if (tid < 32) fl[tid] = 0;
    __syncthreads();
    const size_t rbase = ((size_t)(b * SS + qb * 128)) * SS + tq * 1024 + tid * 4;
    #pragma unroll 1
    for (int r = 0; r < 128; ++r) {
      float4 v = *(const float4*)&mask[rbase + (size_t)r * SS];
      int nz = (v.x != 0.f) | (v.y != 0.f) | (v.z != 0.f) | (v.w != 0.f);
      nz |= __shfl_xor(nz, 1);
      nz |= __shfl_xor(nz, 2);
      nz |= __shfl_xor(nz, 4);
      if (nz && ((tid & 7) == 0)) atomicOr(&fl[tid >> 3], 1);
    }
    __syncthreads();
    if (tid < 32)
      flags[((size_t)(b * 32 + qb)) * 128 + tq * 32 + tid] = (unsigned char)fl[tid];
    return;
  }

  // ---- proj64 body ----
  const int bid = blockIdx.x - 512;
  const int b = bid & 3;
  const int s0 = (bid >> 2) * 64;

  #pragma unroll
  for (int i = 0; i < 4; ++i) {
    int idx = tid + 256 * i;
    int r = idx >> 4, c = (idx & 15) * 4;
    *(float4*)&xs[r][c] = *(const float4*)&x[((size_t)b * SS + s0 + r) * EE + c];
    *(float4*)&gs[r][c] = *(const float4*)&G[(size_t)r * 64 + c];
    *(float4*)&wfs[r][c] = *(const float4*)&Wf[(size_t)r * 64 + c];
  }
  if (tid < 64) { g2s[tid] = g2[tid]; bfs[tid] = bf[tid]; }
  __syncthreads();

  const int d = tid & 63, sg = tid >> 6;
  // u = x @ G
  {
    float acc[16];
    #pragma unroll
    for (int i = 0; i < 16; ++i) acc[i] = 0.f;
    for (int e = 0; e < EE; ++e) {
      float gv = gs[e][d];
      #pragma unroll
      for (int i = 0; i < 16; ++i) acc[i] += xs[sg * 16 + i][e] * gv;
    }
    #pragma unroll
    for (int i = 0; i < 16; ++i)
      ubuf[((size_t)b * SS + s0 + sg * 16 + i) * 64 + d] = f2h(acc[i]);
  }
  // vw = (x @ Wf + bf)^T
  {
    float acc[16];
    #pragma unroll
    for (int i = 0; i < 16; ++i) acc[i] = bfs[d];
    for (int e = 0; e < EE; ++e) {
      float wv = wfs[e][d];
      #pragma unroll
      for (int i = 0; i < 16; ++i) acc[i] += xs[sg * 16 + i][e] * wv;
    }
    u16* dst = vwt + ((size_t)b * 64 + d) * SS + s0 + sg * 16;
    union { uint4 u[2]; u16 hh[16]; } o;
    #pragma unroll
    for (int i = 0; i < 16; ++i) o.hh[i] = f2h(acc[i]);
    *(uint4*)dst = o.u[0];
    *(uint4*)(dst + 8) = o.u[1];
  }
  // c = x @ g2
  if (tid < 64) {
    float cc = 0.f;
    #pragma unroll 8
    for (int e = 0; e < EE; ++e) cc += xs[tid][e] * g2s[e];
    cbuf[(size_t)b * SS + s0 + tid] = cc;
  }
  // xh = fp16(x)
  #pragma unroll
  for (int i = 0; i < 16; ++i) {
    int idx = tid + 256 * i;
    int r = idx >> 6, dd = idx & 63;
    xh[((size_t)b * SS + s0 + r) * 64 + dd] = f2h(xs[r][dd]);
  }
}

// ---------------- K3: flash attention v15 (barrier-free; K frags from L2) ----------------
// scores = u_i . x_j + c_j (+ mask). 512 blocks x 512 thr (8 warps x 16q),
// no LDS K-tile: each lane reads its A-fragment of xh directly from L2
// (same pattern as vwf). ZERO barriers/waitcnts in the loop -> pure TLP.
// LDS: Ps[8][16][72] = 18 KiB only.
__global__ __launch_bounds__(512) void attn_fwd(
    const u16* __restrict__ ubuf, const u16* __restrict__ xh,
    const u16* __restrict__ vwt, const float* __restrict__ cbuf,
    const float* __restrict__ mask, const unsigned char* __restrict__ flags,
    float* __restrict__ opart, float* __restrict__ stats) {
  __shared__ u16 PsS[8 * 16 * 72];

  const int tid = threadIdx.x;
  const int lane = tid & 63;
  const int w = tid >> 6;  // 0..7
  const int lrow = lane & 15, lhi = lane >> 4;

  const int bid = blockIdx.x;
  const int grp = bid & 15;
  const int b = grp >> 2, qt = grp & 3;
  const int qb = bid >> 4;
  const int q0 = qb * 128;
  const int tbase = qt * (SS / 4);

  const int qrow = q0 + w * 16 + lrow;

  // ---- u -> registers (B-operand frags, D=64 -> 2 kk steps) ----
  f16x8 qreg[2];
  {
    const u16* qg = ubuf + ((size_t)b * SS + qrow) * 64 + lhi * 8;
    qreg[0] = *(const f16x8*)(qg);
    qreg[1] = *(const f16x8*)(qg + 32);
  }

  float m_reg = -3.0e38f, l_reg = 0.f;
  f32x4 acc[4];
  #pragma unroll
  for (int f = 0; f < 4; ++f) acc[f] = (f32x4){0.f, 0.f, 0.f, 0.f};

  const u16* vwb = vwt + (size_t)b * 64 * SS;
  const u16* xb = xh + ((size_t)b * SS) * 64;
  const float* cb = cbuf + (size_t)b * SS;
  const size_t mrow_base = ((size_t)b * SS + qrow) * SS;
  const unsigned char* flg = flags + ((size_t)(b * 32 + qb)) * 128 + qt * 32;

  u16* PsW = PsS + w * 1152;  // warp-private [16][72]

  #pragma unroll 1
  for (int it = 0; it < NQT; ++it) {
    const int t0 = tbase + it * KVBLK;

    // --- QK^T swapped over D=64: K A-frags straight from L2 ---
    f32x4 s[4];
    #pragma unroll
    for (int ch = 0; ch < 4; ++ch) s[ch] = (f32x4){0.f, 0.f, 0.f, 0.f};
    {
      const u16* kg = xb + (size_t)(t0 + lrow) * 64 + lhi * 8;
      #pragma unroll
      for (int kk = 0; kk < 2; ++kk) {
        #pragma unroll
        for (int ch = 0; ch < 4; ++ch) {
          f16x8 kf = *(const f16x8*)(kg + (size_t)(ch * 16) * 64 + kk * 32);
          s[ch] = __builtin_amdgcn_mfma_f32_16x16x32_f16(kf, qreg[kk], s[ch], 0, 0, 0);
        }
      }
    }

    // --- column bias c_j ---
    #pragma unroll
    for (int ch = 0; ch < 4; ++ch) {
      const float4 cv = *(const float4*)&cb[t0 + ch * 16 + lhi * 4];
      s[ch][0] += cv.x; s[ch][1] += cv.y; s[ch][2] += cv.z; s[ch][3] += cv.w;
    }
    // --- mask add (block-sparse gated) ---
    if (flg[2 * it] | flg[2 * it + 1]) {
      #pragma unroll
      for (int ch = 0; ch < 4; ++ch) {
        const float4 mv = *(const float4*)&mask[mrow_base + t0 + ch * 16 + lhi * 4];
        s[ch][0] += mv.x; s[ch][1] += mv.y; s[ch][2] += mv.z; s[ch][3] += mv.w;
      }
    }

    // --- in-warp softmax over 64 t ---
    float pmax = -3.0e38f;
    #pragma unroll
    for (int ch = 0; ch < 4; ++ch)
      pmax = fmaxf(pmax, fmaxf(fmaxf(s[ch][0], s[ch][1]), fmaxf(s[ch][2], s[ch][3])));
    pmax = fmaxf(pmax, __shfl_xor(pmax, 16));
    pmax = fmaxf(pmax, __shfl_xor(pmax, 32));

    if (__any(pmax - m_reg > 8.0f)) {  // defer-max (T13)
      float mn = fmaxf(m_reg, pmax);
      float al = __expf(m_reg - mn);
      m_reg = mn;
      l_reg *= al;
      float av[4];
      #pragma unroll
      for (int r = 0; r < 4; ++r) av[r] = __shfl(al, lhi * 4 + r);
      #pragma unroll
      for (int f = 0; f < 4; ++f)
        #pragma unroll
        for (int r = 0; r < 4; ++r) acc[f][r] *= av[r];
    }

    float psum = 0.f;
    #pragma unroll
    for (int ch = 0; ch < 4; ++ch) {
      #pragma unroll
      for (int r = 0; r < 4; ++r) s[ch][r] = __expf(s[ch][r] - m_reg);
      psum += (s[ch][0] + s[ch][1]) + (s[ch][2] + s[ch][3]);
    }
    psum += __shfl_xor(psum, 16);
    psum += __shfl_xor(psum, 32);
    l_reg += psum;

    // --- VW fragments (L2 reads): 4 d-frags x 2 t-halves ---
    uint4 vwf[8];
    #pragma unroll
    for (int f = 0; f < 4; ++f) {
      const u16* vp = vwb + ((size_t)(lrow + 16 * f)) * SS + t0 + lhi * 8;
      vwf[2 * f] = *(const uint4*)(vp);
      vwf[2 * f + 1] = *(const uint4*)(vp + 32);
    }

    // --- P -> warp-private LDS roundtrip ---
    #pragma unroll
    for (int ch = 0; ch < 4; ++ch) {
      uint2 pw;
      pw.x = (u32)f2h(s[ch][0]) | ((u32)f2h(s[ch][1]) << 16);
      pw.y = (u32)f2h(s[ch][2]) | ((u32)f2h(s[ch][3]) << 16);
      *(uint2*)&PsW[lrow * 72 + ch * 16 + lhi * 4] = pw;
    }
    f16x8 pa0 = *(const f16x8*)&PsW[lrow * 72 + lhi * 8];
    f16x8 pa1 = *(const f16x8*)&PsW[lrow * 72 + 32 + lhi * 8];

    // --- PV: O += P @ VW (t=64 -> 8 MFMA) ---
    #pragma unroll
    for (int f = 0; f < 4; ++f) {
      f16x8 b0 = __builtin_bit_cast(f16x8, vwf[2 * f]);
      f16x8 b1 = __builtin_bit_cast(f16x8, vwf[2 * f + 1]);
      acc[f] = __builtin_amdgcn_mfma_f32_16x16x32_f16(pa0, b0, acc[f], 0, 0, 0);
      acc[f] = __builtin_amdgcn_mfma_f32_16x16x32_f16(pa1, b1, acc[f], 0, 0, 0);
    }
  }

  // ---- epilogue: normalized partial (fp32) + (m, l) stats ----
  if (lhi == 0) {
    float2* st = (float2*)stats;
    st[(size_t)qt * (BB * SS) + (size_t)b * SS + q0 + w * 16 + lrow] =
        make_float2(m_reg, l_reg);
  }
  float rl[4];
  #pragma unroll
  for (int r = 0; r < 4; ++r) rl[r] = 1.0f / __shfl(l_reg, lhi * 4 + r);
  #pragma unroll
  for (int r = 0; r < 4; ++r) {
    size_t base = ((size_t)qt * (BB * SS) + (size_t)b * SS +
                   (size_t)(q0 + w * 16 + lhi * 4 + r)) * 64 + (size_t)lrow;
    #pragma unroll
    for (int f = 0; f < 4; ++f) opart[base + f * 16] = acc[f][r] * rl[r];
  }
}

// ---------------- K4: merge 4 KV-quarters, add bo ----------------
__global__ __launch_bounds__(256) void merge4(
    const float* __restrict__ opart, const float* __restrict__ stats,
    const float* __restrict__ bo, float* __restrict__ out) {
  const int gid = blockIdx.x * 256 + threadIdx.x;
  const int row = gid >> 3;
  const int c8 = (gid & 7) * 8;
  const float2* st = (const float2*)stats;
  float2 sq[4];
  #pragma unroll
  for (int q = 0; q < 4; ++q) sq[q] = st[(size_t)q * (BB * SS) + row];
  float M = fmaxf(fmaxf(sq[0].x, sq[1].x), fmaxf(sq[2].x, sq[3].x));
  float wv[4], Ssum = 0.f;
  #pragma unroll
  for (int q = 0; q < 4; ++q) {
    wv[q] = __expf(sq[q].x - M) * sq[q].y;
    Ssum += wv[q];
  }
  const float inv = 0.35355339059327373f / Ssum;
  #pragma unroll
  for (int q = 0; q < 4; ++q) wv[q] *= inv;

  float o[8];
  #pragma unroll
  for (int j = 0; j < 8; ++j) o[j] = bo[c8 + j];
  #pragma unroll
  for (int q = 0; q < 4; ++q) {
    const float* op = opart + ((size_t)q * (BB * SS) + row) * 64 + c8;
    float4 a = *(const float4*)op;
    float4 bq4 = *(const float4*)(op + 4);
    o[0] += wv[q] * a.x; o[1] += wv[q] * a.y; o[2] += wv[q] * a.z; o[3] += wv[q] * a.w;
    o[4] += wv[q] * bq4.x; o[5] += wv[q] * bq4.y; o[6] += wv[q] * bq4.z; o[7] += wv[q] * bq4.w;
  }
  float* dst = out + (size_t)row * EE + c8;
  *(float4*)dst = make_float4(o[0], o[1], o[2], o[3]);
  *(float4*)(dst + 4) = make_float4(o[4], o[5], o[6], o[7]);
}

extern "C" void kernel_launch(void* const* d_in, const int* in_sizes, int n_in,
                              void* d_out, int out_size, void* d_ws, size_t ws_size,
                              hipStream_t stream) {
  const float* x = (const float*)d_in[0];
  const float* mask = (const float*)d_in[1];
  const float* Wq = (const float*)d_in[2];
  const float* bq = (const float*)d_in[3];
  const float* Wk = (const float*)d_in[4];
  const float* bk = (const float*)d_in[5];  // folded out: row-const cancels in softmax
  const float* Wv = (const float*)d_in[6];
  const float* bv = (const float*)d_in[7];
  const float* Wo = (const float*)d_in[8];
  const float* bo = (const float*)d_in[9];
  float* out = (float*)d_out;
  (void)bk;

  const size_t N64 = (size_t)BB * SS * 64;
  u16* ubuf = (u16*)d_ws;
  u16* xhh = ubuf + N64;
  u16* vwt = xhh + N64;
  float* cbuf = (float*)(vwt + N64);
  float* G = cbuf + (size_t)BB * SS;
  float* g2 = G + 64 * 64;
  float* Wf = g2 + 64;
  float* bf = Wf + 64 * 64;
  float* opart = bf + 64;                        // 4 * BB*SS*64 f32
  float* st = opart + (size_t)4 * BB * SS * 64;  // 4 * BB*SS float2
  unsigned char* flags = (unsigned char*)(st + (size_t)8 * BB * SS);  // 16 KB

  wgfuse<<<130, 256, 0, stream>>>(Wq, bq, Wk, Wv, bv, Wo, G, g2, Wf, bf);
  prep<<<512 + BB * SS / 64, 256, 0, stream>>>(x, G, g2, Wf, bf, mask,
                                               ubuf, xhh, cbuf, vwt, flags);
  attn_fwd<<<512, 512, 0, stream>>>(ubuf, xhh, vwt, cbuf, mask, flags, opart, st);
  merge4<<<BB * SS * 8 / 256, 256, 0, stream>>>(opart, st, bo, out);
}

// Round 20
// 165.770 us; speedup vs baseline: 1.4570x; 1.4570x over previous
//
#include <hip/hip_runtime.h>
#include <hip/hip_bf16.h>

#define BB 4
#define SS 4096
#define EE 64
#define DD 512
#define KVBLK 64
#define NQT 16  // 64-wide KV tiles per quarter

typedef __attribute__((ext_vector_type(4))) float f32x4;
typedef __attribute__((ext_vector_type(8))) _Float16 f16x8;
typedef unsigned short u16;
typedef unsigned int u32;

__device__ __forceinline__ u16 f2h(float f) {
  _Float16 h = (_Float16)f;
  return __builtin_bit_cast(u16, h);
}
__device__ __forceinline__ float h2f(u16 b) {
  return (float)__builtin_bit_cast(_Float16, b);
}

__device__ __forceinline__ void async16(const void* g, void* l) {
  __builtin_amdgcn_global_load_lds(
      (const __attribute__((address_space(1))) void*)g,
      (__attribute__((address_space(3))) void*)l, 16, 0, 0);
}

// ---------------- K1: fused weight-fold: G=Wq@Wk^T, g2=Wk@bq, Wf=Wv@Wo, bf=bv@Wo ----
__global__ __launch_bounds__(256) void wgfuse(
    const float* __restrict__ Wq, const float* __restrict__ bq,
    const float* __restrict__ Wk, const float* __restrict__ Wv,
    const float* __restrict__ bv, const float* __restrict__ Wo,
    float* __restrict__ G, float* __restrict__ g2,
    float* __restrict__ Wf, float* __restrict__ bf) {
  __shared__ float red[4][64];
  const int tid = threadIdx.x;
  const int d = tid & 63, kq = tid >> 6;
  const int e = blockIdx.x;
  float a = 0.f;
  if (e < 65) {
    const float* src = (e < 64) ? &Wq[(size_t)e * DD] : bq;
    #pragma unroll 4
    for (int k = kq * 128; k < (kq + 1) * 128; ++k)
      a += src[k] * Wk[(size_t)d * DD + k];
  } else {
    const int e2 = e - 65;
    const float* src = (e2 < 64) ? &Wv[(size_t)e2 * DD] : bv;
    #pragma unroll 4
    for (int k = kq * 128; k < (kq + 1) * 128; ++k)
      a += src[k] * Wo[(size_t)k * EE + d];
  }
  red[kq][d] = a;
  __syncthreads();
  if (tid < 64) {
    float s = (red[0][tid] + red[1][tid]) + (red[2][tid] + red[3][tid]);
    if (e < 64) G[e * 64 + tid] = s;
    else if (e == 64) g2[tid] = s;
    else if (e < 129) Wf[(e - 65) * EE + tid] = s;
    else bf[tid] = s;
  }
}

// ---------------- K2: proj64: u=x@G (fp16), c=x@g2, xh=fp16(x), VWt=(x@Wf+bf)^T ----
__global__ __launch_bounds__(256) void proj64(
    const float* __restrict__ x, const float* __restrict__ G,
    const float* __restrict__ g2, const float* __restrict__ Wf,
    const float* __restrict__ bf, u16* __restrict__ ubuf,
    u16* __restrict__ xh, float* __restrict__ cbuf, u16* __restrict__ vwt) {
  __shared__ float xs[64][EE];
  __shared__ float gs[EE][64];
  __shared__ float wfs[EE][64];
  __shared__ float g2s[64];
  __shared__ float bfs[64];
  const int tid = threadIdx.x;
  const int b = blockIdx.x & 3;
  const int s0 = (blockIdx.x >> 2) * 64;

  #pragma unroll
  for (int i = 0; i < 4; ++i) {
    int idx = tid + 256 * i;
    int r = idx >> 4, c = (idx & 15) * 4;
    *(float4*)&xs[r][c] = *(const float4*)&x[((size_t)b * SS + s0 + r) * EE + c];
    *(float4*)&gs[r][c] = *(const float4*)&G[(size_t)r * 64 + c];
    *(float4*)&wfs[r][c] = *(const float4*)&Wf[(size_t)r * 64 + c];
  }
  if (tid < 64) { g2s[tid] = g2[tid]; bfs[tid] = bf[tid]; }
  __syncthreads();

  const int d = tid & 63, sg = tid >> 6;
  // u = x @ G
  {
    float acc[16];
    #pragma unroll
    for (int i = 0; i < 16; ++i) acc[i] = 0.f;
    for (int e = 0; e < EE; ++e) {
      float gv = gs[e][d];
      #pragma unroll
      for (int i = 0; i < 16; ++i) acc[i] += xs[sg * 16 + i][e] * gv;
    }
    #pragma unroll
    for (int i = 0; i < 16; ++i)
      ubuf[((size_t)b * SS + s0 + sg * 16 + i) * 64 + d] = f2h(acc[i]);
  }
  // vw = (x @ Wf + bf)^T
  {
    float acc[16];
    #pragma unroll
    for (int i = 0; i < 16; ++i) acc[i] = bfs[d];
    for (int e = 0; e < EE; ++e) {
      float wv = wfs[e][d];
      #pragma unroll
      for (int i = 0; i < 16; ++i) acc[i] += xs[sg * 16 + i][e] * wv;
    }
    u16* dst = vwt + ((size_t)b * 64 + d) * SS + s0 + sg * 16;
    union { uint4 u[2]; u16 hh[16]; } o;
    #pragma unroll
    for (int i = 0; i < 16; ++i) o.hh[i] = f2h(acc[i]);
    *(uint4*)dst = o.u[0];
    *(uint4*)(dst + 8) = o.u[1];
  }
  // c = x @ g2
  if (tid < 64) {
    float cc = 0.f;
    #pragma unroll 8
    for (int e = 0; e < EE; ++e) cc += xs[tid][e] * g2s[e];
    cbuf[(size_t)b * SS + s0 + tid] = cc;
  }
  // xh = fp16(x)
  #pragma unroll
  for (int i = 0; i < 16; ++i) {
    int idx = tid + 256 * i;
    int r = idx >> 6, dd = idx & 63;
    xh[((size_t)b * SS + s0 + r) * 64 + dd] = f2h(xs[r][dd]);
  }
}

// ---------------- K3: flash attention v16 (round-18 loop + in-kernel mask scan) ----
// scores = u_i . x_j + c_j (+ mask). 512 blocks x 512 thr (8 warps x 16q).
// PROLOGUE: block streams its own 128q x 1024t mask region (contiguous 4KB/row
// bursts) -> 32 LDS flags; loop gates mask work off LDS (no flags global trip).
// Loop: LDS x-tile dbuf via async16 at tile top, 1 vmcnt+barrier per tile.
// LDS: Ks[2][64][64] 16K | Ps[8][16][72] 18K (dynamic) + fl[32] static.
__global__ __launch_bounds__(512, 4) void attn_fwd(
    const u16* __restrict__ ubuf, const u16* __restrict__ xh,
    const u16* __restrict__ vwt, const float* __restrict__ cbuf,
    const float* __restrict__ mask,
    float* __restrict__ opart, float* __restrict__ stats) {
  extern __shared__ char smem[];
  u16* PsS = (u16*)(smem + 16384);
  __shared__ int fl[32];

  const int tid = threadIdx.x;
  const int lane = tid & 63;
  const int w = tid >> 6;  // 0..7
  const int lrow = lane & 15, lhi = lane >> 4;

  const int bid = blockIdx.x;
  const int grp = bid & 15;
  const int b = grp >> 2, qt = grp & 3;
  const int qb = bid >> 4;
  const int q0 = qb * 128;
  const int tbase = qt * (SS / 4);

  const int qrow = q0 + w * 16 + lrow;

  // ---- u -> registers (B-operand frags, D=64 -> 2 kk steps) ----
  f16x8 qreg[2];
  {
    const u16* qg = ubuf + ((size_t)b * SS + qrow) * 64 + lhi * 8;
    qreg[0] = *(const f16x8*)(qg);
    qreg[1] = *(const f16x8*)(qg + 32);
  }

  // stage a 64x64 fp16 x-tile (8KB): 512 threads x 16B.
  auto stage_k = [&](int t0n, int buf) {
    const char* kg = (const char*)(xh + ((size_t)b * SS + t0n) * 64);
    const int row = w * 8 + (lane >> 3);
    const int ch = lane & 7;
    async16(kg + (size_t)row * 128 + ((ch * 16) ^ ((row & 7) << 4)),
            (char*)smem + buf * 8192 + row * 128);
  };

  float m_reg = -3.0e38f, l_reg = 0.f;
  f32x4 acc[4];
  #pragma unroll
  for (int f = 0; f < 4; ++f) acc[f] = (f32x4){0.f, 0.f, 0.f, 0.f};

  const u16* vwb = vwt + (size_t)b * 64 * SS;
  const float* cb = cbuf + (size_t)b * SS;
  const size_t mrow_base = ((size_t)b * SS + qrow) * SS;

  // ---- prologue: stage K(0); scan this block's mask region -> fl[32] ----
  stage_k(tbase, 0);
  if (tid < 32) fl[tid] = 0;
  __syncthreads();
  {
    // 512 threads = 128 rows x 4 chunks of 256 floats (contiguous 1KB each)
    const int r = tid >> 2, cq = tid & 3;
    const float* mrow =
        mask + ((size_t)(b * SS + q0 + r)) * SS + tbase + cq * 256;
    int nzm = 0;
    #pragma unroll 8
    for (int i = 0; i < 64; ++i) {
      float4 v = *(const float4*)&mrow[i * 4];
      int nz = (v.x != 0.f) | (v.y != 0.f) | (v.z != 0.f) | (v.w != 0.f);
      nzm |= nz << (i >> 3);  // 8 float4 = one 32-t subtile
    }
    if (nzm) {
      #pragma unroll
      for (int s8 = 0; s8 < 8; ++s8)
        if (nzm & (1 << s8)) atomicOr(&fl[cq * 8 + s8], 1);
    }
  }
  asm volatile("s_waitcnt vmcnt(0)" ::: "memory");
  __syncthreads();

  u16* PsW = PsS + w * 1152;  // warp-private [16][72]
  const int kswz = (lrow & 7) << 4;

  #pragma unroll 1
  for (int it = 0; it < NQT; ++it) {
    const int buf = it & 1;
    const int t0 = tbase + it * KVBLK;

    // --- stage NEXT x-tile (full-tile cover) ---
    if (it + 1 < NQT) stage_k(t0 + KVBLK, buf ^ 1);

    // --- QK^T swapped over D=64: 4 t-chains x 2 kk ---
    f32x4 s[4];
    #pragma unroll
    for (int ch = 0; ch < 4; ++ch) s[ch] = (f32x4){0.f, 0.f, 0.f, 0.f};
    {
      const char* kpb = (const char*)smem + buf * 8192 + lrow * 128;
      __builtin_amdgcn_s_setprio(1);
      #pragma unroll
      for (int kk = 0; kk < 2; ++kk) {
        int off = (kk * 64 + lhi * 16) ^ kswz;
        #pragma unroll
        for (int ch = 0; ch < 4; ++ch) {
          f16x8 kf = *(const f16x8*)(kpb + ch * 2048 + off);
          s[ch] = __builtin_amdgcn_mfma_f32_16x16x32_f16(kf, qreg[kk], s[ch], 0, 0, 0);
        }
      }
      __builtin_amdgcn_s_setprio(0);
    }

    // --- column bias c_j ---
    #pragma unroll
    for (int ch = 0; ch < 4; ++ch) {
      const float4 cv = *(const float4*)&cb[t0 + ch * 16 + lhi * 4];
      s[ch][0] += cv.x; s[ch][1] += cv.y; s[ch][2] += cv.z; s[ch][3] += cv.w;
    }
    // --- mask add (gated by LDS flags; two 32-t flags per 64-t tile) ---
    if (fl[2 * it] | fl[2 * it + 1]) {
      #pragma unroll
      for (int ch = 0; ch < 4; ++ch) {
        const float4 mv = *(const float4*)&mask[mrow_base + t0 + ch * 16 + lhi * 4];
        s[ch][0] += mv.x; s[ch][1] += mv.y; s[ch][2] += mv.z; s[ch][3] += mv.w;
      }
    }

    // --- in-warp softmax over 64 t ---
    float pmax = -3.0e38f;
    #pragma unroll
    for (int ch = 0; ch < 4; ++ch)
      pmax = fmaxf(pmax, fmaxf(fmaxf(s[ch][0], s[ch][1]), fmaxf(s[ch][2], s[ch][3])));
    pmax = fmaxf(pmax, __shfl_xor(pmax, 16));
    pmax = fmaxf(pmax, __shfl_xor(pmax, 32));

    if (__any(pmax - m_reg > 8.0f)) {  // defer-max (T13)
      float mn = fmaxf(m_reg, pmax);
      float al = __expf(m_reg - mn);
      m_reg = mn;
      l_reg *= al;
      float av[4];
      #pragma unroll
      for (int r = 0; r < 4; ++r) av[r] = __shfl(al, lhi * 4 + r);
      #pragma unroll
      for (int f = 0; f < 4; ++f)
        #pragma unroll
        for (int r = 0; r < 4; ++r) acc[f][r] *= av[r];
    }

    float psum = 0.f;
    #pragma unroll
    for (int ch = 0; ch < 4; ++ch) {
      #pragma unroll
      for (int r = 0; r < 4; ++r) s[ch][r] = __expf(s[ch][r] - m_reg);
      psum += (s[ch][0] + s[ch][1]) + (s[ch][2] + s[ch][3]);
    }
    psum += __shfl_xor(psum, 16);
    psum += __shfl_xor(psum, 32);
    l_reg += psum;

    // --- VW fragments (L2 reads): 4 d-frags x 2 t-halves ---
    uint4 vwf[8];
    #pragma unroll
    for (int f = 0; f < 4; ++f) {
      const u16* vp = vwb + ((size_t)(lrow + 16 * f)) * SS + t0 + lhi * 8;
      vwf[2 * f] = *(const uint4*)(vp);
      vwf[2 * f + 1] = *(const uint4*)(vp + 32);
    }

    // --- P -> warp-private LDS roundtrip ---
    #pragma unroll
    for (int ch = 0; ch < 4; ++ch) {
      uint2 pw;
      pw.x = (u32)f2h(s[ch][0]) | ((u32)f2h(s[ch][1]) << 16);
      pw.y = (u32)f2h(s[ch][2]) | ((u32)f2h(s[ch][3]) << 16);
      *(uint2*)&PsW[lrow * 72 + ch * 16 + lhi * 4] = pw;
    }
    f16x8 pa0 = *(const f16x8*)&PsW[lrow * 72 + lhi * 8];
    f16x8 pa1 = *(const f16x8*)&PsW[lrow * 72 + 32 + lhi * 8];

    // --- PV: O += P @ VW (t=64 -> 8 MFMA) ---
    __builtin_amdgcn_s_setprio(1);
    #pragma unroll
    for (int f = 0; f < 4; ++f) {
      f16x8 b0 = __builtin_bit_cast(f16x8, vwf[2 * f]);
      f16x8 b1 = __builtin_bit_cast(f16x8, vwf[2 * f + 1]);
      acc[f] = __builtin_amdgcn_mfma_f32_16x16x32_f16(pa0, b0, acc[f], 0, 0, 0);
      acc[f] = __builtin_amdgcn_mfma_f32_16x16x32_f16(pa1, b1, acc[f], 0, 0, 0);
    }
    __builtin_amdgcn_s_setprio(0);

    // --- single sync point per tile ---
    asm volatile("s_waitcnt vmcnt(0)" ::: "memory");
    __syncthreads();
  }

  // ---- epilogue: normalized partial (fp32) + (m, l) stats ----
  if (lhi == 0) {
    float2* st = (float2*)stats;
    st[(size_t)qt * (BB * SS) + (size_t)b * SS + q0 + w * 16 + lrow] =
        make_float2(m_reg, l_reg);
  }
  float rl[4];
  #pragma unroll
  for (int r = 0; r < 4; ++r) rl[r] = 1.0f / __shfl(l_reg, lhi * 4 + r);
  #pragma unroll
  for (int r = 0; r < 4; ++r) {
    size_t base = ((size_t)qt * (BB * SS) + (size_t)b * SS +
                   (size_t)(q0 + w * 16 + lhi * 4 + r)) * 64 + (size_t)lrow;
    #pragma unroll
    for (int f = 0; f < 4; ++f) opart[base + f * 16] = acc[f][r] * rl[r];
  }
}

// ---------------- K4: merge 4 KV-quarters, add bo ----------------
__global__ __launch_bounds__(256) void merge4(
    const float* __restrict__ opart, const float* __restrict__ stats,
    const float* __restrict__ bo, float* __restrict__ out) {
  const int gid = blockIdx.x * 256 + threadIdx.x;
  const int row = gid >> 3;
  const int c8 = (gid & 7) * 8;
  const float2* st = (const float2*)stats;
  float2 sq[4];
  #pragma unroll
  for (int q = 0; q < 4; ++q) sq[q] = st[(size_t)q * (BB * SS) + row];
  float M = fmaxf(fmaxf(sq[0].x, sq[1].x), fmaxf(sq[2].x, sq[3].x));
  float wv[4], Ssum = 0.f;
  #pragma unroll
  for (int q = 0; q < 4; ++q) {
    wv[q] = __expf(sq[q].x - M) * sq[q].y;
    Ssum += wv[q];
  }
  const float inv = 0.35355339059327373f / Ssum;
  #pragma unroll
  for (int q = 0; q < 4; ++q) wv[q] *= inv;

  float o[8];
  #pragma unroll
  for (int j = 0; j < 8; ++j) o[j] = bo[c8 + j];
  #pragma unroll
  for (int q = 0; q < 4; ++q) {
    const float* op = opart + ((size_t)q * (BB * SS) + row) * 64 + c8;
    float4 a = *(const float4*)op;
    float4 bq4 = *(const float4*)(op + 4);
    o[0] += wv[q] * a.x; o[1] += wv[q] * a.y; o[2] += wv[q] * a.z; o[3] += wv[q] * a.w;
    o[4] += wv[q] * bq4.x; o[5] += wv[q] * bq4.y; o[6] += wv[q] * bq4.z; o[7] += wv[q] * bq4.w;
  }
  float* dst = out + (size_t)row * EE + c8;
  *(float4*)dst = make_float4(o[0], o[1], o[2], o[3]);
  *(float4*)(dst + 4) = make_float4(o[4], o[5], o[6], o[7]);
}

extern "C" void kernel_launch(void* const* d_in, const int* in_sizes, int n_in,
                              void* d_out, int out_size, void* d_ws, size_t ws_size,
                              hipStream_t stream) {
  const float* x = (const float*)d_in[0];
  const float* mask = (const float*)d_in[1];
  const float* Wq = (const float*)d_in[2];
  const float* bq = (const float*)d_in[3];
  const float* Wk = (const float*)d_in[4];
  const float* bk = (const float*)d_in[5];  // folded out: row-const cancels in softmax
  const float* Wv = (const float*)d_in[6];
  const float* bv = (const float*)d_in[7];
  const float* Wo = (const float*)d_in[8];
  const float* bo = (const float*)d_in[9];
  float* out = (float*)d_out;
  (void)bk;

  const size_t N64 = (size_t)BB * SS * 64;
  u16* ubuf = (u16*)d_ws;
  u16* xhh = ubuf + N64;
  u16* vwt = xhh + N64;
  float* cbuf = (float*)(vwt + N64);
  float* G = cbuf + (size_t)BB * SS;
  float* g2 = G + 64 * 64;
  float* Wf = g2 + 64;
  float* bf = Wf + 64 * 64;
  float* opart = bf + 64;                        // 4 * BB*SS*64 f32
  float* st = opart + (size_t)4 * BB * SS * 64;  // 4 * BB*SS float2

  wgfuse<<<130, 256, 0, stream>>>(Wq, bq, Wk, Wv, bv, Wo, G, g2, Wf, bf);
  proj64<<<BB * SS / 64, 256, 0, stream>>>(x, G, g2, Wf, bf, ubuf, xhh, cbuf, vwt);
  attn_fwd<<<512, 512, 34816, stream>>>(ubuf, xhh, vwt, cbuf, mask, opart, st);
  merge4<<<BB * SS * 8 / 256, 256, 0, stream>>>(opart, st, bo, out);
}

// Round 21
// 140.823 us; speedup vs baseline: 1.7151x; 1.1772x over previous
//
#include <hip/hip_runtime.h>
#include <hip/hip_bf16.h>

#define BB 4
#define SS 4096
#define EE 64
#define DD 512
#define KVBLK 64
#define NQT 16  // 64-wide KV tiles per quarter

typedef __attribute__((ext_vector_type(4))) float f32x4;
typedef __attribute__((ext_vector_type(8))) _Float16 f16x8;
typedef unsigned short u16;
typedef unsigned int u32;

__device__ __forceinline__ u16 f2h(float f) {
  _Float16 h = (_Float16)f;
  return __builtin_bit_cast(u16, h);
}
__device__ __forceinline__ float h2f(u16 b) {
  return (float)__builtin_bit_cast(_Float16, b);
}

__device__ __forceinline__ void async16(const void* g, void* l) {
  __builtin_amdgcn_global_load_lds(
      (const __attribute__((address_space(1))) void*)g,
      (__attribute__((address_space(3))) void*)l, 16, 0, 0);
}

// ---------------- K1: fused weight-fold: G=Wq@Wk^T, g2=Wk@bq, Wf=Wv@Wo, bf=bv@Wo ----
__global__ __launch_bounds__(256) void wgfuse(
    const float* __restrict__ Wq, const float* __restrict__ bq,
    const float* __restrict__ Wk, const float* __restrict__ Wv,
    const float* __restrict__ bv, const float* __restrict__ Wo,
    float* __restrict__ G, float* __restrict__ g2,
    float* __restrict__ Wf, float* __restrict__ bf) {
  __shared__ float red[4][64];
  const int tid = threadIdx.x;
  const int d = tid & 63, kq = tid >> 6;
  const int e = blockIdx.x;
  float a = 0.f;
  if (e < 65) {
    const float* src = (e < 64) ? &Wq[(size_t)e * DD] : bq;
    #pragma unroll 4
    for (int k = kq * 128; k < (kq + 1) * 128; ++k)
      a += src[k] * Wk[(size_t)d * DD + k];
  } else {
    const int e2 = e - 65;
    const float* src = (e2 < 64) ? &Wv[(size_t)e2 * DD] : bv;
    #pragma unroll 4
    for (int k = kq * 128; k < (kq + 1) * 128; ++k)
      a += src[k] * Wo[(size_t)k * EE + d];
  }
  red[kq][d] = a;
  __syncthreads();
  if (tid < 64) {
    float s = (red[0][tid] + red[1][tid]) + (red[2][tid] + red[3][tid]);
    if (e < 64) G[e * 64 + tid] = s;
    else if (e == 64) g2[tid] = s;
    else if (e < 129) Wf[(e - 65) * EE + tid] = s;
    else bf[tid] = s;
  }
}

// ---------------- K2: proj64: u=x@G (fp16), c=x@g2, xh=fp16(x), VWt=(x@Wf+bf)^T ----
__global__ __launch_bounds__(256) void proj64(
    const float* __restrict__ x, const float* __restrict__ G,
    const float* __restrict__ g2, const float* __restrict__ Wf,
    const float* __restrict__ bf, u16* __restrict__ ubuf,
    u16* __restrict__ xh, float* __restrict__ cbuf, u16* __restrict__ vwt) {
  __shared__ float xs[64][EE];
  __shared__ float gs[EE][64];
  __shared__ float wfs[EE][64];
  __shared__ float g2s[64];
  __shared__ float bfs[64];
  const int tid = threadIdx.x;
  const int b = blockIdx.x & 3;
  const int s0 = (blockIdx.x >> 2) * 64;

  #pragma unroll
  for (int i = 0; i < 4; ++i) {
    int idx = tid + 256 * i;
    int r = idx >> 4, c = (idx & 15) * 4;
    *(float4*)&xs[r][c] = *(const float4*)&x[((size_t)b * SS + s0 + r) * EE + c];
    *(float4*)&gs[r][c] = *(const float4*)&G[(size_t)r * 64 + c];
    *(float4*)&wfs[r][c] = *(const float4*)&Wf[(size_t)r * 64 + c];
  }
  if (tid < 64) { g2s[tid] = g2[tid]; bfs[tid] = bf[tid]; }
  __syncthreads();

  const int d = tid & 63, sg = tid >> 6;
  // u = x @ G
  {
    float acc[16];
    #pragma unroll
    for (int i = 0; i < 16; ++i) acc[i] = 0.f;
    for (int e = 0; e < EE; ++e) {
      float gv = gs[e][d];
      #pragma unroll
      for (int i = 0; i < 16; ++i) acc[i] += xs[sg * 16 + i][e] * gv;
    }
    #pragma unroll
    for (int i = 0; i < 16; ++i)
      ubuf[((size_t)b * SS + s0 + sg * 16 + i) * 64 + d] = f2h(acc[i]);
  }
  // vw = (x @ Wf + bf)^T
  {
    float acc[16];
    #pragma unroll
    for (int i = 0; i < 16; ++i) acc[i] = bfs[d];
    for (int e = 0; e < EE; ++e) {
      float wv = wfs[e][d];
      #pragma unroll
      for (int i = 0; i < 16; ++i) acc[i] += xs[sg * 16 + i][e] * wv;
    }
    u16* dst = vwt + ((size_t)b * 64 + d) * SS + s0 + sg * 16;
    union { uint4 u[2]; u16 hh[16]; } o;
    #pragma unroll
    for (int i = 0; i < 16; ++i) o.hh[i] = f2h(acc[i]);
    *(uint4*)dst = o.u[0];
    *(uint4*)(dst + 8) = o.u[1];
  }
  // c = x @ g2
  if (tid < 64) {
    float cc = 0.f;
    #pragma unroll 8
    for (int e = 0; e < EE; ++e) cc += xs[tid][e] * g2s[e];
    cbuf[(size_t)b * SS + s0 + tid] = cc;
  }
  // xh = fp16(x)
  #pragma unroll
  for (int i = 0; i < 16; ++i) {
    int idx = tid + 256 * i;
    int r = idx >> 6, dd = idx & 63;
    xh[((size_t)b * SS + s0 + r) * 64 + dd] = f2h(xs[r][dd]);
  }
}

// ---------------- K3: flash attention v17 (coalesced in-kernel mask scan) ----------------
// scores = u_i . x_j + c_j (+ mask). 512 blocks x 512 thr (8 warps x 16q).
// PROLOGUE: block streams its 128q x 1024t mask region with COALESCED bursts
// (each wave = contiguous 1KB; thread's subtile flag is constant -> 1 atomicOr).
// Loop: LDS x-tile dbuf via async16 at tile top, 1 vmcnt+barrier per tile.
// LDS: Ks[2][64][64] 16K | Ps[8][16][72] 18K (dynamic) + fl[32] static.
__global__ __launch_bounds__(512, 4) void attn_fwd(
    const u16* __restrict__ ubuf, const u16* __restrict__ xh,
    const u16* __restrict__ vwt, const float* __restrict__ cbuf,
    const float* __restrict__ mask,
    float* __restrict__ opart, float* __restrict__ stats) {
  extern __shared__ char smem[];
  u16* PsS = (u16*)(smem + 16384);
  __shared__ int fl[32];

  const int tid = threadIdx.x;
  const int lane = tid & 63;
  const int w = tid >> 6;  // 0..7
  const int lrow = lane & 15, lhi = lane >> 4;

  const int bid = blockIdx.x;
  const int grp = bid & 15;
  const int b = grp >> 2, qt = grp & 3;
  const int qb = bid >> 4;
  const int q0 = qb * 128;
  const int tbase = qt * (SS / 4);

  const int qrow = q0 + w * 16 + lrow;

  // ---- u -> registers (B-operand frags, D=64 -> 2 kk steps) ----
  f16x8 qreg[2];
  {
    const u16* qg = ubuf + ((size_t)b * SS + qrow) * 64 + lhi * 8;
    qreg[0] = *(const f16x8*)(qg);
    qreg[1] = *(const f16x8*)(qg + 32);
  }

  // stage a 64x64 fp16 x-tile (8KB): 512 threads x 16B.
  auto stage_k = [&](int t0n, int buf) {
    const char* kg = (const char*)(xh + ((size_t)b * SS + t0n) * 64);
    const int row = w * 8 + (lane >> 3);
    const int ch = lane & 7;
    async16(kg + (size_t)row * 128 + ((ch * 16) ^ ((row & 7) << 4)),
            (char*)smem + buf * 8192 + row * 128);
  };

  float m_reg = -3.0e38f, l_reg = 0.f;
  f32x4 acc[4];
  #pragma unroll
  for (int f = 0; f < 4; ++f) acc[f] = (f32x4){0.f, 0.f, 0.f, 0.f};

  const u16* vwb = vwt + (size_t)b * 64 * SS;
  const float* cb = cbuf + (size_t)b * SS;
  const size_t mrow_base = ((size_t)b * SS + qrow) * SS;

  // ---- prologue: stage K(0); COALESCED scan of block's mask region -> fl[32] ----
  stage_k(tbase, 0);
  if (tid < 32) fl[tid] = 0;
  __syncthreads();
  {
    // iteration i: threads cover rows {2i, 2i+1}; thread reads float4 at
    // column (tid&255)*4 -> each wave = contiguous 1KB burst.
    const int half = tid >> 8;       // 0..1
    const int col4 = (tid & 255) * 4;
    const float* mbase2 =
        mask + ((size_t)(b * SS + q0 + half)) * SS + tbase + col4;
    int nzm = 0;
    #pragma unroll 8
    for (int i = 0; i < 64; ++i) {
      float4 v = *(const float4*)(mbase2 + (size_t)(2 * i) * SS);
      nzm |= (v.x != 0.f) | (v.y != 0.f) | (v.z != 0.f) | (v.w != 0.f);
    }
    if (nzm) atomicOr(&fl[(tid & 255) >> 3], 1);
  }
  asm volatile("s_waitcnt vmcnt(0)" ::: "memory");
  __syncthreads();

  u16* PsW = PsS + w * 1152;  // warp-private [16][72]
  const int kswz = (lrow & 7) << 4;

  #pragma unroll 1
  for (int it = 0; it < NQT; ++it) {
    const int buf = it & 1;
    const int t0 = tbase + it * KVBLK;

    // --- stage NEXT x-tile (full-tile cover) ---
    if (it + 1 < NQT) stage_k(t0 + KVBLK, buf ^ 1);

    // --- QK^T swapped over D=64: 4 t-chains x 2 kk ---
    f32x4 s[4];
    #pragma unroll
    for (int ch = 0; ch < 4; ++ch) s[ch] = (f32x4){0.f, 0.f, 0.f, 0.f};
    {
      const char* kpb = (const char*)smem + buf * 8192 + lrow * 128;
      __builtin_amdgcn_s_setprio(1);
      #pragma unroll
      for (int kk = 0; kk < 2; ++kk) {
        int off = (kk * 64 + lhi * 16) ^ kswz;
        #pragma unroll
        for (int ch = 0; ch < 4; ++ch) {
          f16x8 kf = *(const f16x8*)(kpb + ch * 2048 + off);
          s[ch] = __builtin_amdgcn_mfma_f32_16x16x32_f16(kf, qreg[kk], s[ch], 0, 0, 0);
        }
      }
      __builtin_amdgcn_s_setprio(0);
    }

    // --- column bias c_j ---
    #pragma unroll
    for (int ch = 0; ch < 4; ++ch) {
      const float4 cv = *(const float4*)&cb[t0 + ch * 16 + lhi * 4];
      s[ch][0] += cv.x; s[ch][1] += cv.y; s[ch][2] += cv.z; s[ch][3] += cv.w;
    }
    // --- mask add (gated by LDS flags; two 32-t flags per 64-t tile) ---
    if (fl[2 * it] | fl[2 * it + 1]) {
      #pragma unroll
      for (int ch = 0; ch < 4; ++ch) {
        const float4 mv = *(const float4*)&mask[mrow_base + t0 + ch * 16 + lhi * 4];
        s[ch][0] += mv.x; s[ch][1] += mv.y; s[ch][2] += mv.z; s[ch][3] += mv.w;
      }
    }

    // --- in-warp softmax over 64 t ---
    float pmax = -3.0e38f;
    #pragma unroll
    for (int ch = 0; ch < 4; ++ch)
      pmax = fmaxf(pmax, fmaxf(fmaxf(s[ch][0], s[ch][1]), fmaxf(s[ch][2], s[ch][3])));
    pmax = fmaxf(pmax, __shfl_xor(pmax, 16));
    pmax = fmaxf(pmax, __shfl_xor(pmax, 32));

    if (__any(pmax - m_reg > 8.0f)) {  // defer-max (T13)
      float mn = fmaxf(m_reg, pmax);
      float al = __expf(m_reg - mn);
      m_reg = mn;
      l_reg *= al;
      float av[4];
      #pragma unroll
      for (int r = 0; r < 4; ++r) av[r] = __shfl(al, lhi * 4 + r);
      #pragma unroll
      for (int f = 0; f < 4; ++f)
        #pragma unroll
        for (int r = 0; r < 4; ++r) acc[f][r] *= av[r];
    }

    float psum = 0.f;
    #pragma unroll
    for (int ch = 0; ch < 4; ++ch) {
      #pragma unroll
      for (int r = 0; r < 4; ++r) s[ch][r] = __expf(s[ch][r] - m_reg);
      psum += (s[ch][0] + s[ch][1]) + (s[ch][2] + s[ch][3]);
    }
    psum += __shfl_xor(psum, 16);
    psum += __shfl_xor(psum, 32);
    l_reg += psum;

    // --- VW fragments (L2 reads): 4 d-frags x 2 t-halves ---
    uint4 vwf[8];
    #pragma unroll
    for (int f = 0; f < 4; ++f) {
      const u16* vp = vwb + ((size_t)(lrow + 16 * f)) * SS + t0 + lhi * 8;
      vwf[2 * f] = *(const uint4*)(vp);
      vwf[2 * f + 1] = *(const uint4*)(vp + 32);
    }

    // --- P -> warp-private LDS roundtrip ---
    #pragma unroll
    for (int ch = 0; ch < 4; ++ch) {
      uint2 pw;
      pw.x = (u32)f2h(s[ch][0]) | ((u32)f2h(s[ch][1]) << 16);
      pw.y = (u32)f2h(s[ch][2]) | ((u32)f2h(s[ch][3]) << 16);
      *(uint2*)&PsW[lrow * 72 + ch * 16 + lhi * 4] = pw;
    }
    f16x8 pa0 = *(const f16x8*)&PsW[lrow * 72 + lhi * 8];
    f16x8 pa1 = *(const f16x8*)&PsW[lrow * 72 + 32 + lhi * 8];

    // --- PV: O += P @ VW (t=64 -> 8 MFMA) ---
    __builtin_amdgcn_s_setprio(1);
    #pragma unroll
    for (int f = 0; f < 4; ++f) {
      f16x8 b0 = __builtin_bit_cast(f16x8, vwf[2 * f]);
      f16x8 b1 = __builtin_bit_cast(f16x8, vwf[2 * f + 1]);
      acc[f] = __builtin_amdgcn_mfma_f32_16x16x32_f16(pa0, b0, acc[f], 0, 0, 0);
      acc[f] = __builtin_amdgcn_mfma_f32_16x16x32_f16(pa1, b1, acc[f], 0, 0, 0);
    }
    __builtin_amdgcn_s_setprio(0);

    // --- single sync point per tile ---
    asm volatile("s_waitcnt vmcnt(0)" ::: "memory");
    __syncthreads();
  }

  // ---- epilogue: normalized partial (fp32) + (m, l) stats ----
  if (lhi == 0) {
    float2* st = (float2*)stats;
    st[(size_t)qt * (BB * SS) + (size_t)b * SS + q0 + w * 16 + lrow] =
        make_float2(m_reg, l_reg);
  }
  float rl[4];
  #pragma unroll
  for (int r = 0; r < 4; ++r) rl[r] = 1.0f / __shfl(l_reg, lhi * 4 + r);
  #pragma unroll
  for (int r = 0; r < 4; ++r) {
    size_t base = ((size_t)qt * (BB * SS) + (size_t)b * SS +
                   (size_t)(q0 + w * 16 + lhi * 4 + r)) * 64 + (size_t)lrow;
    #pragma unroll
    for (int f = 0; f < 4; ++f) opart[base + f * 16] = acc[f][r] * rl[r];
  }
}

// ---------------- K4: merge 4 KV-quarters, add bo ----------------
__global__ __launch_bounds__(256) void merge4(
    const float* __restrict__ opart, const float* __restrict__ stats,
    const float* __restrict__ bo, float* __restrict__ out) {
  const int gid = blockIdx.x * 256 + threadIdx.x;
  const int row = gid >> 3;
  const int c8 = (gid & 7) * 8;
  const float2* st = (const float2*)stats;
  float2 sq[4];
  #pragma unroll
  for (int q = 0; q < 4; ++q) sq[q] = st[(size_t)q * (BB * SS) + row];
  float M = fmaxf(fmaxf(sq[0].x, sq[1].x), fmaxf(sq[2].x, sq[3].x));
  float wv[4], Ssum = 0.f;
  #pragma unroll
  for (int q = 0; q < 4; ++q) {
    wv[q] = __expf(sq[q].x - M) * sq[q].y;
    Ssum += wv[q];
  }
  const float inv = 0.35355339059327373f / Ssum;
  #pragma unroll
  for (int q = 0; q < 4; ++q) wv[q] *= inv;

  float o[8];
  #pragma unroll
  for (int j = 0; j < 8; ++j) o[j] = bo[c8 + j];
  #pragma unroll
  for (int q = 0; q < 4; ++q) {
    const float* op = opart + ((size_t)q * (BB * SS) + row) * 64 + c8;
    float4 a = *(const float4*)op;
    float4 bq4 = *(const float4*)(op + 4);
    o[0] += wv[q] * a.x; o[1] += wv[q] * a.y; o[2] += wv[q] * a.z; o[3] += wv[q] * a.w;
    o[4] += wv[q] * bq4.x; o[5] += wv[q] * bq4.y; o[6] += wv[q] * bq4.z; o[7] += wv[q] * bq4.w;
  }
  float* dst = out + (size_t)row * EE + c8;
  *(float4*)dst = make_float4(o[0], o[1], o[2], o[3]);
  *(float4*)(dst + 4) = make_float4(o[4], o[5], o[6], o[7]);
}

extern "C" void kernel_launch(void* const* d_in, const int* in_sizes, int n_in,
                              void* d_out, int out_size, void* d_ws, size_t ws_size,
                              hipStream_t stream) {
  const float* x = (const float*)d_in[0];
  const float* mask = (const float*)d_in[1];
  const float* Wq = (const float*)d_in[2];
  const float* bq = (const float*)d_in[3];
  const float* Wk = (const float*)d_in[4];
  const float* bk = (const float*)d_in[5];  // folded out: row-const cancels in softmax
  const float* Wv = (const float*)d_in[6];
  const float* bv = (const float*)d_in[7];
  const float* Wo = (const float*)d_in[8];
  const float* bo = (const float*)d_in[9];
  float* out = (float*)d_out;
  (void)bk;

  const size_t N64 = (size_t)BB * SS * 64;
  u16* ubuf = (u16*)d_ws;
  u16* xhh = ubuf + N64;
  u16* vwt = xhh + N64;
  float* cbuf = (float*)(vwt + N64);
  float* G = cbuf + (size_t)BB * SS;
  float* g2 = G + 64 * 64;
  float* Wf = g2 + 64;
  float* bf = Wf + 64 * 64;
  float* opart = bf + 64;                        // 4 * BB*SS*64 f32
  float* st = opart + (size_t)4 * BB * SS * 64;  // 4 * BB*SS float2

  wgfuse<<<130, 256, 0, stream>>>(Wq, bq, Wk, Wv, bv, Wo, G, g2, Wf, bf);
  proj64<<<BB * SS / 64, 256, 0, stream>>>(x, G, g2, Wf, bf, ubuf, xhh, cbuf, vwt);
  attn_fwd<<<512, 512, 34816, stream>>>(ubuf, xhh, vwt, cbuf, mask, opart, st);
  merge4<<<BB * SS * 8 / 256, 256, 0, stream>>>(opart, st, bo, out);
}

// Round 22
// 140.141 us; speedup vs baseline: 1.7234x; 1.0049x over previous
//
#include <hip/hip_runtime.h>
#include <hip/hip_bf16.h>

#define BB 4
#define SS 4096
#define EE 64
#define DD 512
#define KVBLK 64
#define NQT 16  // 64-wide KV tiles per quarter

typedef __attribute__((ext_vector_type(4))) float f32x4;
typedef __attribute__((ext_vector_type(8))) _Float16 f16x8;
typedef unsigned short u16;
typedef unsigned int u32;
typedef unsigned long long u64;

__device__ __forceinline__ u16 f2h(float f) {
  _Float16 h = (_Float16)f;
  return __builtin_bit_cast(u16, h);
}
__device__ __forceinline__ float h2f(u16 b) {
  return (float)__builtin_bit_cast(_Float16, b);
}

__device__ __forceinline__ void async16(const void* g, void* l) {
  __builtin_amdgcn_global_load_lds(
      (const __attribute__((address_space(1))) void*)g,
      (__attribute__((address_space(3))) void*)l, 16, 0, 0);
}

// ---------------- K1: fused weight-fold: G=Wq@Wk^T, g2=Wk@bq, Wf=Wv@Wo, bf=bv@Wo ----
__global__ __launch_bounds__(256) void wgfuse(
    const float* __restrict__ Wq, const float* __restrict__ bq,
    const float* __restrict__ Wk, const float* __restrict__ Wv,
    const float* __restrict__ bv, const float* __restrict__ Wo,
    float* __restrict__ G, float* __restrict__ g2,
    float* __restrict__ Wf, float* __restrict__ bf) {
  __shared__ float red[4][64];
  const int tid = threadIdx.x;
  const int d = tid & 63, kq = tid >> 6;
  const int e = blockIdx.x;
  float a = 0.f;
  if (e < 65) {
    const float* src = (e < 64) ? &Wq[(size_t)e * DD] : bq;
    #pragma unroll 4
    for (int k = kq * 128; k < (kq + 1) * 128; ++k)
      a += src[k] * Wk[(size_t)d * DD + k];
  } else {
    const int e2 = e - 65;
    const float* src = (e2 < 64) ? &Wv[(size_t)e2 * DD] : bv;
    #pragma unroll 4
    for (int k = kq * 128; k < (kq + 1) * 128; ++k)
      a += src[k] * Wo[(size_t)k * EE + d];
  }
  red[kq][d] = a;
  __syncthreads();
  if (tid < 64) {
    float s = (red[0][tid] + red[1][tid]) + (red[2][tid] + red[3][tid]);
    if (e < 64) G[e * 64 + tid] = s;
    else if (e == 64) g2[tid] = s;
    else if (e < 129) Wf[(e - 65) * EE + tid] = s;
    else bf[tid] = s;
  }
}

// ---------------- K2: proj64: u=x@G (fp16), c=x@g2, xh=fp16(x), VWt=(x@Wf+bf)^T ----
__global__ __launch_bounds__(256) void proj64(
    const float* __restrict__ x, const float* __restrict__ G,
    const float* __restrict__ g2, const float* __restrict__ Wf,
    const float* __restrict__ bf, u16* __restrict__ ubuf,
    u16* __restrict__ xh, float* __restrict__ cbuf, u16* __restrict__ vwt) {
  __shared__ float xs[64][EE];
  __shared__ float gs[EE][64];
  __shared__ float wfs[EE][64];
  __shared__ float g2s[64];
  __shared__ float bfs[64];
  const int tid = threadIdx.x;
  const int b = blockIdx.x & 3;
  const int s0 = (blockIdx.x >> 2) * 64;

  #pragma unroll
  for (int i = 0; i < 4; ++i) {
    int idx = tid + 256 * i;
    int r = idx >> 4, c = (idx & 15) * 4;
    *(float4*)&xs[r][c] = *(const float4*)&x[((size_t)b * SS + s0 + r) * EE + c];
    *(float4*)&gs[r][c] = *(const float4*)&G[(size_t)r * 64 + c];
    *(float4*)&wfs[r][c] = *(const float4*)&Wf[(size_t)r * 64 + c];
  }
  if (tid < 64) { g2s[tid] = g2[tid]; bfs[tid] = bf[tid]; }
  __syncthreads();

  const int d = tid & 63, sg = tid >> 6;
  // u = x @ G
  {
    float acc[16];
    #pragma unroll
    for (int i = 0; i < 16; ++i) acc[i] = 0.f;
    for (int e = 0; e < EE; ++e) {
      float gv = gs[e][d];
      #pragma unroll
      for (int i = 0; i < 16; ++i) acc[i] += xs[sg * 16 + i][e] * gv;
    }
    #pragma unroll
    for (int i = 0; i < 16; ++i)
      ubuf[((size_t)b * SS + s0 + sg * 16 + i) * 64 + d] = f2h(acc[i]);
  }
  // vw = (x @ Wf + bf)^T
  {
    float acc[16];
    #pragma unroll
    for (int i = 0; i < 16; ++i) acc[i] = bfs[d];
    for (int e = 0; e < EE; ++e) {
      float wv = wfs[e][d];
      #pragma unroll
      for (int i = 0; i < 16; ++i) acc[i] += xs[sg * 16 + i][e] * wv;
    }
    u16* dst = vwt + ((size_t)b * 64 + d) * SS + s0 + sg * 16;
    union { uint4 u[2]; u16 hh[16]; } o;
    #pragma unroll
    for (int i = 0; i < 16; ++i) o.hh[i] = f2h(acc[i]);
    *(uint4*)dst = o.u[0];
    *(uint4*)(dst + 8) = o.u[1];
  }
  // c = x @ g2
  if (tid < 64) {
    float cc = 0.f;
    #pragma unroll 8
    for (int e = 0; e < EE; ++e) cc += xs[tid][e] * g2s[e];
    cbuf[(size_t)b * SS + s0 + tid] = cc;
  }
  // xh = fp16(x)
  #pragma unroll
  for (int i = 0; i < 16; ++i) {
    int idx = tid + 256 * i;
    int r = idx >> 6, dd = idx & 63;
    xh[((size_t)b * SS + s0 + r) * 64 + dd] = f2h(xs[r][dd]);
  }
}

// ---------------- K3: flash attention v18 (warp-local ballot mask scan) ----------------
// scores = u_i . x_j + c_j (+ mask). 512 blocks x 512 thr (8 warps x 16q).
// PROLOGUE: warp w scans ITS 16 rows x 1024t of mask (1KB contiguous bursts,
// 16 loads in flight) -> 4 x __ballot masks in SGPRs. No LDS flags, no atomics,
// no extra barriers. Loop gates mask work off wave-uniform bit tests.
// Loop: LDS x-tile dbuf via async16 at tile top, 1 vmcnt+barrier per tile.
// LDS: Ks[2][64][64] 16K | Ps[8][16][72] 18K (dynamic).
__global__ __launch_bounds__(512, 4) void attn_fwd(
    const u16* __restrict__ ubuf, const u16* __restrict__ xh,
    const u16* __restrict__ vwt, const float* __restrict__ cbuf,
    const float* __restrict__ mask,
    float* __restrict__ opart, float* __restrict__ stats) {
  extern __shared__ char smem[];
  u16* PsS = (u16*)(smem + 16384);

  const int tid = threadIdx.x;
  const int lane = tid & 63;
  const int w = tid >> 6;  // 0..7
  const int lrow = lane & 15, lhi = lane >> 4;

  const int bid = blockIdx.x;
  const int grp = bid & 15;
  const int b = grp >> 2, qt = grp & 3;
  const int qb = bid >> 4;
  const int q0 = qb * 128;
  const int tbase = qt * (SS / 4);

  const int qrow = q0 + w * 16 + lrow;

  // ---- u -> registers (B-operand frags, D=64 -> 2 kk steps) ----
  f16x8 qreg[2];
  {
    const u16* qg = ubuf + ((size_t)b * SS + qrow) * 64 + lhi * 8;
    qreg[0] = *(const f16x8*)(qg);
    qreg[1] = *(const f16x8*)(qg + 32);
  }

  // stage a 64x64 fp16 x-tile (8KB): 512 threads x 16B.
  auto stage_k = [&](int t0n, int buf) {
    const char* kg = (const char*)(xh + ((size_t)b * SS + t0n) * 64);
    const int row = w * 8 + (lane >> 3);
    const int ch = lane & 7;
    async16(kg + (size_t)row * 128 + ((ch * 16) ^ ((row & 7) << 4)),
            (char*)smem + buf * 8192 + row * 128);
  };

  float m_reg = -3.0e38f, l_reg = 0.f;
  f32x4 acc[4];
  #pragma unroll
  for (int f = 0; f < 4; ++f) acc[f] = (f32x4){0.f, 0.f, 0.f, 0.f};

  const u16* vwb = vwt + (size_t)b * 64 * SS;
  const float* cb = cbuf + (size_t)b * SS;
  const size_t mrow_base = ((size_t)b * SS + qrow) * SS;

  // ---- prologue: stage K(0); warp-local ballot scan of mask rows ----
  stage_k(tbase, 0);
  u64 bal0, bal1, bal2, bal3;
  {
    // warp w scans rows [q0+w*16, q0+w*16+16) x [tbase, tbase+1024).
    // pass p covers cols [p*256, p*256+256): wave burst = 1KB contiguous.
    const float* mwbase =
        mask + ((size_t)(b * SS + q0 + w * 16)) * SS + tbase + lane * 4;
    int nz0 = 0, nz1 = 0, nz2 = 0, nz3 = 0;
    #pragma unroll 4
    for (int r = 0; r < 16; ++r) {
      const float* mr = mwbase + (size_t)r * SS;
      float4 v0 = *(const float4*)(mr);
      float4 v1 = *(const float4*)(mr + 256);
      float4 v2 = *(const float4*)(mr + 512);
      float4 v3 = *(const float4*)(mr + 768);
      nz0 |= (v0.x != 0.f) | (v0.y != 0.f) | (v0.z != 0.f) | (v0.w != 0.f);
      nz1 |= (v1.x != 0.f) | (v1.y != 0.f) | (v1.z != 0.f) | (v1.w != 0.f);
      nz2 |= (v2.x != 0.f) | (v2.y != 0.f) | (v2.z != 0.f) | (v2.w != 0.f);
      nz3 |= (v3.x != 0.f) | (v3.y != 0.f) | (v3.z != 0.f) | (v3.w != 0.f);
    }
    bal0 = __ballot(nz0);
    bal1 = __ballot(nz1);
    bal2 = __ballot(nz2);
    bal3 = __ballot(nz3);
  }
  asm volatile("s_waitcnt vmcnt(0)" ::: "memory");
  __syncthreads();

  u16* PsW = PsS + w * 1152;  // warp-private [16][72]
  const int kswz = (lrow & 7) << 4;

  #pragma unroll 1
  for (int it = 0; it < NQT; ++it) {
    const int buf = it & 1;
    const int t0 = tbase + it * KVBLK;

    // --- stage NEXT x-tile (full-tile cover) ---
    if (it + 1 < NQT) stage_k(t0 + KVBLK, buf ^ 1);

    // --- QK^T swapped over D=64: 4 t-chains x 2 kk ---
    f32x4 s[4];
    #pragma unroll
    for (int ch = 0; ch < 4; ++ch) s[ch] = (f32x4){0.f, 0.f, 0.f, 0.f};
    {
      const char* kpb = (const char*)smem + buf * 8192 + lrow * 128;
      __builtin_amdgcn_s_setprio(1);
      #pragma unroll
      for (int kk = 0; kk < 2; ++kk) {
        int off = (kk * 64 + lhi * 16) ^ kswz;
        #pragma unroll
        for (int ch = 0; ch < 4; ++ch) {
          f16x8 kf = *(const f16x8*)(kpb + ch * 2048 + off);
          s[ch] = __builtin_amdgcn_mfma_f32_16x16x32_f16(kf, qreg[kk], s[ch], 0, 0, 0);
        }
      }
      __builtin_amdgcn_s_setprio(0);
    }

    // --- column bias c_j ---
    #pragma unroll
    for (int ch = 0; ch < 4; ++ch) {
      const float4 cv = *(const float4*)&cb[t0 + ch * 16 + lhi * 4];
      s[ch][0] += cv.x; s[ch][1] += cv.y; s[ch][2] += cv.z; s[ch][3] += cv.w;
    }
    // --- mask add (warp-local ballot gate; wave-uniform bit test) ---
    {
      u64 balv = (it < 4) ? bal0 : (it < 8) ? bal1 : (it < 12) ? bal2 : bal3;
      if ((balv >> (16 * (it & 3))) & 0xFFFFull) {
        #pragma unroll
        for (int ch = 0; ch < 4; ++ch) {
          const float4 mv = *(const float4*)&mask[mrow_base + t0 + ch * 16 + lhi * 4];
          s[ch][0] += mv.x; s[ch][1] += mv.y; s[ch][2] += mv.z; s[ch][3] += mv.w;
        }
      }
    }

    // --- in-warp softmax over 64 t ---
    float pmax = -3.0e38f;
    #pragma unroll
    for (int ch = 0; ch < 4; ++ch)
      pmax = fmaxf(pmax, fmaxf(fmaxf(s[ch][0], s[ch][1]), fmaxf(s[ch][2], s[ch][3])));
    pmax = fmaxf(pmax, __shfl_xor(pmax, 16));
    pmax = fmaxf(pmax, __shfl_xor(pmax, 32));

    if (__any(pmax - m_reg > 8.0f)) {  // defer-max (T13)
      float mn = fmaxf(m_reg, pmax);
      float al = __expf(m_reg - mn);
      m_reg = mn;
      l_reg *= al;
      float av[4];
      #pragma unroll
      for (int r = 0; r < 4; ++r) av[r] = __shfl(al, lhi * 4 + r);
      #pragma unroll
      for (int f = 0; f < 4; ++f)
        #pragma unroll
        for (int r = 0; r < 4; ++r) acc[f][r] *= av[r];
    }

    float psum = 0.f;
    #pragma unroll
    for (int ch = 0; ch < 4; ++ch) {
      #pragma unroll
      for (int r = 0; r < 4; ++r) s[ch][r] = __expf(s[ch][r] - m_reg);
      psum += (s[ch][0] + s[ch][1]) + (s[ch][2] + s[ch][3]);
    }
    psum += __shfl_xor(psum, 16);
    psum += __shfl_xor(psum, 32);
    l_reg += psum;

    // --- VW fragments (L2 reads): 4 d-frags x 2 t-halves ---
    uint4 vwf[8];
    #pragma unroll
    for (int f = 0; f < 4; ++f) {
      const u16* vp = vwb + ((size_t)(lrow + 16 * f)) * SS + t0 + lhi * 8;
      vwf[2 * f] = *(const uint4*)(vp);
      vwf[2 * f + 1] = *(const uint4*)(vp + 32);
    }

    // --- P -> warp-private LDS roundtrip ---
    #pragma unroll
    for (int ch = 0; ch < 4; ++ch) {
      uint2 pw;
      pw.x = (u32)f2h(s[ch][0]) | ((u32)f2h(s[ch][1]) << 16);
      pw.y = (u32)f2h(s[ch][2]) | ((u32)f2h(s[ch][3]) << 16);
      *(uint2*)&PsW[lrow * 72 + ch * 16 + lhi * 4] = pw;
    }
    f16x8 pa0 = *(const f16x8*)&PsW[lrow * 72 + lhi * 8];
    f16x8 pa1 = *(const f16x8*)&PsW[lrow * 72 + 32 + lhi * 8];

    // --- PV: O += P @ VW (t=64 -> 8 MFMA) ---
    __builtin_amdgcn_s_setprio(1);
    #pragma unroll
    for (int f = 0; f < 4; ++f) {
      f16x8 b0 = __builtin_bit_cast(f16x8, vwf[2 * f]);
      f16x8 b1 = __builtin_bit_cast(f16x8, vwf[2 * f + 1]);
      acc[f] = __builtin_amdgcn_mfma_f32_16x16x32_f16(pa0, b0, acc[f], 0, 0, 0);
      acc[f] = __builtin_amdgcn_mfma_f32_16x16x32_f16(pa1, b1, acc[f], 0, 0, 0);
    }
    __builtin_amdgcn_s_setprio(0);

    // --- single sync point per tile ---
    asm volatile("s_waitcnt vmcnt(0)" ::: "memory");
    __syncthreads();
  }

  // ---- epilogue: normalized partial (fp32) + (m, l) stats ----
  if (lhi == 0) {
    float2* st = (float2*)stats;
    st[(size_t)qt * (BB * SS) + (size_t)b * SS + q0 + w * 16 + lrow] =
        make_float2(m_reg, l_reg);
  }
  float rl[4];
  #pragma unroll
  for (int r = 0; r < 4; ++r) rl[r] = 1.0f / __shfl(l_reg, lhi * 4 + r);
  #pragma unroll
  for (int r = 0; r < 4; ++r) {
    size_t base = ((size_t)qt * (BB * SS) + (size_t)b * SS +
                   (size_t)(q0 + w * 16 + lhi * 4 + r)) * 64 + (size_t)lrow;
    #pragma unroll
    for (int f = 0; f < 4; ++f) opart[base + f * 16] = acc[f][r] * rl[r];
  }
}

// ---------------- K4: merge 4 KV-quarters, add bo ----------------
__global__ __launch_bounds__(256) void merge4(
    const float* __restrict__ opart, const float* __restrict__ stats,
    const float* __restrict__ bo, float* __restrict__ out) {
  const int gid = blockIdx.x * 256 + threadIdx.x;
  const int row = gid >> 3;
  const int c8 = (gid & 7) * 8;
  const float2* st = (const float2*)stats;
  float2 sq[4];
  #pragma unroll
  for (int q = 0; q < 4; ++q) sq[q] = st[(size_t)q * (BB * SS) + row];
  float M = fmaxf(fmaxf(sq[0].x, sq[1].x), fmaxf(sq[2].x, sq[3].x));
  float wv[4], Ssum = 0.f;
  #pragma unroll
  for (int q = 0; q < 4; ++q) {
    wv[q] = __expf(sq[q].x - M) * sq[q].y;
    Ssum += wv[q];
  }
  const float inv = 0.35355339059327373f / Ssum;
  #pragma unroll
  for (int q = 0; q < 4; ++q) wv[q] *= inv;

  float o[8];
  #pragma unroll
  for (int j = 0; j < 8; ++j) o[j] = bo[c8 + j];
  #pragma unroll
  for (int q = 0; q < 4; ++q) {
    const float* op = opart + ((size_t)q * (BB * SS) + row) * 64 + c8;
    float4 a = *(const float4*)op;
    float4 bq4 = *(const float4*)(op + 4);
    o[0] += wv[q] * a.x; o[1] += wv[q] * a.y; o[2] += wv[q] * a.z; o[3] += wv[q] * a.w;
    o[4] += wv[q] * bq4.x; o[5] += wv[q] * bq4.y; o[6] += wv[q] * bq4.z; o[7] += wv[q] * bq4.w;
  }
  float* dst = out + (size_t)row * EE + c8;
  *(float4*)dst = make_float4(o[0], o[1], o[2], o[3]);
  *(float4*)(dst + 4) = make_float4(o[4], o[5], o[6], o[7]);
}

extern "C" void kernel_launch(void* const* d_in, const int* in_sizes, int n_in,
                              void* d_out, int out_size, void* d_ws, size_t ws_size,
                              hipStream_t stream) {
  const float* x = (const float*)d_in[0];
  const float* mask = (const float*)d_in[1];
  const float* Wq = (const float*)d_in[2];
  const float* bq = (const float*)d_in[3];
  const float* Wk = (const float*)d_in[4];
  const float* bk = (const float*)d_in[5];  // folded out: row-const cancels in softmax
  const float* Wv = (const float*)d_in[6];
  const float* bv = (const float*)d_in[7];
  const float* Wo = (const float*)d_in[8];
  const float* bo = (const float*)d_in[9];
  float* out = (float*)d_out;
  (void)bk;

  const size_t N64 = (size_t)BB * SS * 64;
  u16* ubuf = (u16*)d_ws;
  u16* xhh = ubuf + N64;
  u16* vwt = xhh + N64;
  float* cbuf = (float*)(vwt + N64);
  float* G = cbuf + (size_t)BB * SS;
  float* g2 = G + 64 * 64;
  float* Wf = g2 + 64;
  float* bf = Wf + 64 * 64;
  float* opart = bf + 64;                        // 4 * BB*SS*64 f32
  float* st = opart + (size_t)4 * BB * SS * 64;  // 4 * BB*SS float2

  wgfuse<<<130, 256, 0, stream>>>(Wq, bq, Wk, Wv, bv, Wo, G, g2, Wf, bf);
  proj64<<<BB * SS / 64, 256, 0, stream>>>(x, G, g2, Wf, bf, ubuf, xhh, cbuf, vwt);
  attn_fwd<<<512, 512, 34816, stream>>>(ubuf, xhh, vwt, cbuf, mask, opart, st);
  merge4<<<BB * SS * 8 / 256, 256, 0, stream>>>(opart, st, bo, out);
}